// Round 14
// baseline (81.221 us; speedup 1.0000x reference)
//
#include <hip/hip_runtime.h>

typedef unsigned short ushort_t;
typedef __attribute__((ext_vector_type(8))) __bf16 bf16x8;
typedef __attribute__((ext_vector_type(4))) float f32x4;
typedef __attribute__((ext_vector_type(4))) unsigned int u32x4;
typedef __attribute__((ext_vector_type(8))) unsigned short u16x8;

#define NQ 8192
#define NK 8192
#define DD 256
#define NSPLIT 8
#define SEG (NK / NSPLIT)   // 1024 K-rows per split
#define KBLK 64             // K rows per tile (32 KB); 2 tiles per barrier-phase
#define NT (SEG / KBLK)     // 16 tiles per block
#define LOG2E 1.4426950408889634f
#define LN2 0.6931471805599453f

using gptr_t = const __attribute__((address_space(1))) void*;
using lptr_t = __attribute__((address_space(3))) void*;

__device__ __forceinline__ float fexp2(float x) { return __builtin_amdgcn_exp2f(x); }
__device__ __forceinline__ float flog2(float x) { return __builtin_amdgcn_logf(x); }

// round-to-nearest-even fp32 -> bf16
__device__ __forceinline__ ushort_t f2bf(float f) {
  unsigned int u = __builtin_bit_cast(unsigned int, f);
  unsigned int r = 0x7FFFu + ((u >> 16) & 1u);
  return (ushort_t)((u + r) >> 16);
}

// ---------------------------------------------------------------------------
// Kernel 1: W [256x256] fp32 -> W^T bf16
// ---------------------------------------------------------------------------
__global__ __launch_bounds__(256) void transpose_w_kernel(
    const float* __restrict__ Wq, const float* __restrict__ Wk,
    ushort_t* __restrict__ WqT, ushort_t* __restrict__ WkT) {
  int idx = blockIdx.x * 256 + threadIdx.x;
  const float* W = (idx < 65536) ? Wq : Wk;
  ushort_t* WT = (idx < 65536) ? WqT : WkT;
  int e = idx & 65535;
  int d = e >> 8, n = e & 255;
  WT[n * 256 + d] = f2bf(W[d * 256 + n]);
}

// ---------------------------------------------------------------------------
// Kernel 2: projections  OUT_bf16[8192x256] = X_fp32 @ W  (via W^T rows)
// Q additionally scaled by log2(e) so the lse runs in base-2.
// grid (256, 2), 128 threads (2 waves x 16 rows).  z-split removed (R13: it
// re-read X 4x).  Each block reads its 32 X-rows ONCE, W^T stays L2-hot.
// ---------------------------------------------------------------------------
__global__ __launch_bounds__(128) void proj_kernel(
    const float* __restrict__ xq, const float* __restrict__ xk,
    const ushort_t* __restrict__ WqT, const ushort_t* __restrict__ WkT,
    ushort_t* __restrict__ Qb, ushort_t* __restrict__ Kb) {
  const float* X = (blockIdx.y == 0) ? xq : xk;
  const ushort_t* WT = (blockIdx.y == 0) ? WqT : WkT;
  ushort_t* OUT = (blockIdx.y == 0) ? Qb : Kb;
  const float scale = (blockIdx.y == 0) ? LOG2E : 1.0f;

  const int tid = threadIdx.x;
  const int w = tid >> 6, lane = tid & 63;
  const int g = lane >> 4, c = lane & 15;
  const int rbase = blockIdx.x * 32 + w * 16;

  bf16x8 a[8];
#pragma unroll
  for (int kk = 0; kk < 8; ++kk) {
    const f32x4* px =
        reinterpret_cast<const f32x4*>(X + (size_t)(rbase + c) * DD + kk * 32 + g * 8);
    f32x4 x0 = px[0], x1 = px[1];
    u16x8 v;
#pragma unroll
    for (int j = 0; j < 4; ++j) { v[j] = f2bf(x0[j]); v[4 + j] = f2bf(x1[j]); }
    a[kk] = __builtin_bit_cast(bf16x8, v);
  }

#pragma unroll
  for (int ct = 0; ct < 16; ++ct) {
    f32x4 acc = {0.f, 0.f, 0.f, 0.f};
#pragma unroll
    for (int kk = 0; kk < 8; ++kk) {
      u32x4 bv = *reinterpret_cast<const u32x4*>(
          WT + (size_t)(ct * 16 + c) * DD + kk * 32 + g * 8);
      acc = __builtin_amdgcn_mfma_f32_16x16x32_bf16(
          a[kk], __builtin_bit_cast(bf16x8, bv), acc, 0, 0, 0);
    }
#pragma unroll
    for (int r = 0; r < 4; ++r)
      OUT[(size_t)(rbase + g * 4 + r) * DD + ct * 16 + c] = f2bf(acc[r] * scale);
  }
}

// ---------------------------------------------------------------------------
// Kernel 3: flash-style scores + online base-2 logsumexp partials.
// grid (NQ/128, NSPLIT).  4 waves x 32 Q-rows.  TWO K-tiles [64x256] per
// barrier-phase: stage both buffers -> vmcnt(16) -> barrier -> 256 MFMA
// (both tiles) -> lgkm(0) -> barrier.  16 barriers/block vs R13's 32 --
// targets the ~40k cyc/CU barrier-lockstep residual R13 left intact.
// Fold: 8-score groups (one rescale per 8), placed between STAGE-issue and
// the vmcnt wait.
// ---------------------------------------------------------------------------
__global__ __launch_bounds__(256, 2) void scores_lse_kernel(
    const ushort_t* __restrict__ Qb, const ushort_t* __restrict__ Kb,
    float* __restrict__ pm, float* __restrict__ ps) {
  __shared__ __align__(128) char smem[2][KBLK * 512];  // 64 KB
  const int tid = threadIdx.x;
  const int w = tid >> 6, lane = tid & 63;
  const int g = lane >> 4, c = lane & 15;
  const int qw = blockIdx.x * 128 + w * 32;
  const int j0 = blockIdx.y * SEG;

  // A-frags: 2 row-tiles x 8 k-steps (64 VGPRs, resident whole kernel).
  bf16x8 a[2][8];
#pragma unroll
  for (int rt = 0; rt < 2; ++rt)
#pragma unroll
    for (int kk = 0; kk < 8; ++kk) {
      u32x4 v = *reinterpret_cast<const u32x4*>(
          Qb + (size_t)(qw + rt * 16 + c) * DD + kk * 32 + g * 8);
      a[rt][kk] = __builtin_bit_cast(bf16x8, v);
    }
  asm volatile("s_waitcnt vmcnt(0)" ::: "memory");

  // hoisted per-lane ds_read bases (even/odd kk parity; R7 derivation)
  const int c2 = (c >> 2) & 1;
  const int lbase = c * 512 + ((g ^ (c & 3)) << 4);
  const int base_e = lbase + c2 * 64;
  const int base_o = lbase - c2 * 64;

  float m[2][4], s[2][4];
#pragma unroll
  for (int rt = 0; rt < 2; ++rt)
#pragma unroll
    for (int r = 0; r < 4; ++r) { m[rt][r] = -3.4e38f; s[rt][r] = 0.f; }

  f32x4 accE[2][4], accO[2][4];

  // stage tile t (64 rows, 32 KB): 4 waves x 8 gload_lds(16B) each.
  // LDS[row][ch] = K[row][ch^(row&7)] via swizzled GLOBAL source.
#define STAGE(buf, t)                                                          \
  do {                                                                         \
    const char* kbase_ = (const char*)(Kb + (size_t)(j0 + (t) * KBLK) * DD);   \
    _Pragma("unroll") for (int i_ = 0; i_ < 8; ++i_) {                         \
      int L_ = (w * 8 + i_) * 64 + lane;                                       \
      int row_ = L_ >> 5, ch_ = L_ & 31;                                       \
      const char* src_ = kbase_ + row_ * 512 + ((ch_ ^ (row_ & 7)) * 16);      \
      char* dst_ = &smem[buf][L_ * 16];                                        \
      __builtin_amdgcn_global_load_lds((gptr_t)src_, (lptr_t)dst_, 16, 0, 0);  \
    }                                                                          \
  } while (0)

  // reads+MFMA of one tile into acc set C (zero-init inside)
#define MFMA_TILE(buf, C)                                                      \
  do {                                                                         \
    const char* se_ = &smem[buf][0] + base_e;                                  \
    const char* so_ = &smem[buf][0] + base_o;                                  \
    _Pragma("unroll") for (int rt_ = 0; rt_ < 2; ++rt_)                        \
    _Pragma("unroll") for (int jt_ = 0; jt_ < 4; ++jt_)                        \
        C[rt_][jt_] = (f32x4){0.f, 0.f, 0.f, 0.f};                             \
    _Pragma("unroll") for (int kk_ = 0; kk_ < 8; kk_ += 2) {                   \
      _Pragma("unroll") for (int jt_ = 0; jt_ < 4; ++jt_) {                    \
        bf16x8 be_ = *reinterpret_cast<const bf16x8*>(se_ + jt_ * 8192 + kk_ * 64); \
        bf16x8 bo_ = *reinterpret_cast<const bf16x8*>(so_ + jt_ * 8192 + (kk_ + 1) * 64); \
        C[0][jt_] = __builtin_amdgcn_mfma_f32_16x16x32_bf16(a[0][kk_], be_, C[0][jt_], 0, 0, 0); \
        C[1][jt_] = __builtin_amdgcn_mfma_f32_16x16x32_bf16(a[1][kk_], be_, C[1][jt_], 0, 0, 0); \
        C[0][jt_] = __builtin_amdgcn_mfma_f32_16x16x32_bf16(a[0][kk_ + 1], bo_, C[0][jt_], 0, 0, 0); \
        C[1][jt_] = __builtin_amdgcn_mfma_f32_16x16x32_bf16(a[1][kk_ + 1], bo_, C[1][jt_], 0, 0, 0); \
      }                                                                        \
    }                                                                          \
  } while (0)

  // branchless grouped fold of BOTH acc sets: 8 scores per (rt,r) chain,
  // one rescale exp2 per 8 scores
#define FOLD8                                                                  \
  do {                                                                         \
    _Pragma("unroll") for (int rt_ = 0; rt_ < 2; ++rt_)                        \
    _Pragma("unroll") for (int r_ = 0; r_ < 4; ++r_) {                         \
      float e0_ = accE[rt_][0][r_], e1_ = accE[rt_][1][r_];                    \
      float e2_ = accE[rt_][2][r_], e3_ = accE[rt_][3][r_];                    \
      float o0_ = accO[rt_][0][r_], o1_ = accO[rt_][1][r_];                    \
      float o2_ = accO[rt_][2][r_], o3_ = accO[rt_][3][r_];                    \
      float tmE_ = fmaxf(fmaxf(e0_, e1_), fmaxf(e2_, e3_));                    \
      float tmO_ = fmaxf(fmaxf(o0_, o1_), fmaxf(o2_, o3_));                    \
      float mo_ = m[rt_][r_];                                                  \
      float mn_ = fmaxf(mo_, fmaxf(tmE_, tmO_));                               \
      s[rt_][r_] = s[rt_][r_] * fexp2(mo_ - mn_) +                             \
                   (fexp2(e0_ - mn_) + fexp2(e1_ - mn_) +                      \
                    fexp2(e2_ - mn_) + fexp2(e3_ - mn_)) +                     \
                   (fexp2(o0_ - mn_) + fexp2(o1_ - mn_) +                      \
                    fexp2(o2_ - mn_) + fexp2(o3_ - mn_));                      \
      m[rt_][r_] = mn_;                                                        \
    }                                                                          \
  } while (0)

  // prologue: tiles 0 (buf0) and 1 (buf1)
  STAGE(0, 0);
  STAGE(1, 1);

#pragma unroll 1
  for (int t = 0; t < NT; t += 2) {
    if (t + 2 < NT) {
      STAGE(0, t + 2);                                    // 16 new loads in flight
      STAGE(1, t + 3);
      if (t > 0) FOLD8;                                   // fold prev pair (reg-only)
      asm volatile("s_waitcnt vmcnt(16)" ::: "memory");   // tiles t,t+1 landed
    } else {
      FOLD8;                                              // fold pair t-2,t-1
      asm volatile("s_waitcnt vmcnt(0)" ::: "memory");    // last pair landed
    }
    __builtin_amdgcn_s_barrier();

    MFMA_TILE(0, accE);                                   // tile t
    MFMA_TILE(1, accO);                                   // tile t+1

    // reads of both buffers done, then barrier => safe for next pair's STAGE.
    // NO vmcnt drain: next pair's 16 loads stay in flight across the barrier.
    asm volatile("s_waitcnt lgkmcnt(0)" ::: "memory");
    __builtin_amdgcn_s_barrier();
  }
  FOLD8;  // final pair
#undef STAGE
#undef MFMA_TILE
#undef FOLD8

  // merge the 16 lanes of each group (each held a 4-col-stride slice)
#pragma unroll
  for (int rt = 0; rt < 2; ++rt)
#pragma unroll
    for (int r = 0; r < 4; ++r) {
      float M = m[rt][r], S = s[rt][r];
#pragma unroll
      for (int off = 1; off < 16; off <<= 1) {
        float Mo = __shfl_xor(M, off);
        float So = __shfl_xor(S, off);
        float Mn = fmaxf(M, Mo);
        S = S * fexp2(M - Mn) + So * fexp2(Mo - Mn);
        M = Mn;
      }
      if (c == 0) {
        int row = qw + rt * 16 + g * 4 + r;
        pm[blockIdx.y * NQ + row] = M;
        ps[blockIdx.y * NQ + row] = S;
      }
    }
}

// ---------------------------------------------------------------------------
// Kernel 4a: per-row lse (base-2 partials -> natural), block-sum -> part[64]
// ---------------------------------------------------------------------------
__global__ __launch_bounds__(128) void finalize1_kernel(
    const float* __restrict__ pm, const float* __restrict__ ps,
    float* __restrict__ part) {
  const int tid = threadIdx.x;
  const int row = blockIdx.x * 128 + tid;
  float M = -3.4e38f;
#pragma unroll
  for (int k = 0; k < NSPLIT; ++k) M = fmaxf(M, pm[k * NQ + row]);
  float S = 0.f;
#pragma unroll
  for (int k = 0; k < NSPLIT; ++k) S += ps[k * NQ + row] * fexp2(pm[k * NQ + row] - M);
  float v = LN2 * (M + flog2(S));

  __shared__ float red[128];
  red[tid] = v;
  __syncthreads();
#pragma unroll
  for (int st = 64; st > 0; st >>= 1) {
    if (tid < st) red[tid] += red[tid + st];
    __syncthreads();
  }
  if (tid == 0) part[blockIdx.x] = red[0];
}

// ---------------------------------------------------------------------------
// Kernel 4b: sum 64 partials, negate.
// ---------------------------------------------------------------------------
__global__ __launch_bounds__(64) void finalize2_kernel(
    const float* __restrict__ part, float* __restrict__ out) {
  const int lane = threadIdx.x;
  float v = part[lane];
#pragma unroll
  for (int off = 1; off < 64; off <<= 1) v += __shfl_xor(v, off);
  if (lane == 0) out[0] = -v;
}

// ---------------------------------------------------------------------------
extern "C" void kernel_launch(void* const* d_in, const int* in_sizes, int n_in,
                              void* d_out, int out_size, void* d_ws, size_t ws_size,
                              hipStream_t stream) {
  const float* xq = (const float*)d_in[0];
  const float* xk = (const float*)d_in[1];
  const float* Wq = (const float*)d_in[2];
  const float* Wk = (const float*)d_in[3];

  char* ws = (char*)d_ws;
  // ws: Qb 4MB | Kb 4MB | WqT 128KB | WkT 128KB | pm 256KB | ps 256KB | part 256B
  ushort_t* Qb = (ushort_t*)(ws);
  ushort_t* Kb = (ushort_t*)(ws + (size_t)NQ * DD * 2);
  ushort_t* WqT = (ushort_t*)(ws + (size_t)(NQ + NK) * DD * 2);
  ushort_t* WkT = (ushort_t*)(ws + (size_t)(NQ + NK) * DD * 2 + (size_t)DD * DD * 2);
  float* pm = (float*)(ws + (size_t)(NQ + NK) * DD * 2 + (size_t)2 * DD * DD * 2);
  float* ps = pm + (size_t)NSPLIT * NQ;
  float* part = ps + (size_t)NSPLIT * NQ;

  hipLaunchKernelGGL(transpose_w_kernel, dim3(512), dim3(256), 0, stream, Wq, Wk, WqT, WkT);
  hipLaunchKernelGGL(proj_kernel, dim3(256, 2), dim3(128), 0, stream,
                     xq, xk, WqT, WkT, Qb, Kb);
  hipLaunchKernelGGL(scores_lse_kernel, dim3(NQ / 128, NSPLIT), dim3(256), 0, stream,
                     Qb, Kb, pm, ps);
  hipLaunchKernelGGL(finalize1_kernel, dim3(64), dim3(128), 0, stream, pm, ps, part);
  hipLaunchKernelGGL(finalize2_kernel, dim3(1), dim3(64), 0, stream, part, (float*)d_out);
}

// Round 15
// 62.158 us; speedup vs baseline: 1.3067x; 1.3067x over previous
//
#include <hip/hip_runtime.h>

typedef unsigned short ushort_t;
typedef __attribute__((ext_vector_type(8))) __bf16 bf16x8;
typedef __attribute__((ext_vector_type(4))) float f32x4;
typedef __attribute__((ext_vector_type(4))) unsigned int u32x4;
typedef __attribute__((ext_vector_type(8))) unsigned short u16x8;

#define NQ 8192
#define NK 8192
#define DD 256
#define NSPLIT 8
#define SEG (NK / NSPLIT)   // 1024 K-rows per split
#define KBLK 64             // K rows staged in LDS per tile (32 KB)
#define NT (SEG / KBLK)     // 16 tiles per block
#define LOG2E 1.4426950408889634f
#define LN2 0.6931471805599453f

using gptr_t = const __attribute__((address_space(1))) void*;
using lptr_t = __attribute__((address_space(3))) void*;

__device__ __forceinline__ float fexp2(float x) { return __builtin_amdgcn_exp2f(x); }
__device__ __forceinline__ float flog2(float x) { return __builtin_amdgcn_logf(x); }

// round-to-nearest-even fp32 -> bf16
__device__ __forceinline__ ushort_t f2bf(float f) {
  unsigned int u = __builtin_bit_cast(unsigned int, f);
  unsigned int r = 0x7FFFu + ((u >> 16) & 1u);
  return (ushort_t)((u + r) >> 16);
}

// ---------------------------------------------------------------------------
// Kernel 1: projections OUT_bf16[8192x256] = X_fp32 @ W, transpose FUSED.
// grid (128, 2, 4): x -> 64-row group, y -> Q/K, z -> ct quarter (4 cts).
// Each block stages its 64 W^T rows (cols z*64..z*64+63, all 256 k) into
// LDS as bf16 with the chunk-XOR swizzle (ch ^= n&7), read back as B-frags
// with the scores-kernel pattern (conflict-balanced).  Q scaled by log2e.
// ---------------------------------------------------------------------------
__global__ __launch_bounds__(256) void proj_kernel(
    const float* __restrict__ xq, const float* __restrict__ xk,
    const float* __restrict__ Wq, const float* __restrict__ Wk,
    ushort_t* __restrict__ Qb, ushort_t* __restrict__ Kb) {
  __shared__ __align__(16) char wt_lds[64 * 512];  // 32 KB: 64 cols x 256 k bf16
  const float* X = (blockIdx.y == 0) ? xq : xk;
  const float* W = (blockIdx.y == 0) ? Wq : Wk;
  ushort_t* OUT = (blockIdx.y == 0) ? Qb : Kb;
  const float scale = (blockIdx.y == 0) ? LOG2E : 1.0f;

  const int tid = threadIdx.x;
  const int w = tid >> 6, lane = tid & 63;
  const int g = lane >> 4, c = lane & 15;
  const int rbase = blockIdx.x * 64 + w * 16;
  const int ctbase = blockIdx.z * 4;

  // ---- stage W^T slice: LDS[n][k] = W[k][z*64+n], chunk-swizzled ch^=n&7.
  // thread: n = tid&63, k = i*8 + (tid>>6)*2 (+1) -> packed u32 write.
  {
    const int n_ = tid & 63;
    const int kb = (tid >> 6) * 2;
    const int nglob = blockIdx.z * 64 + n_;
#pragma unroll
    for (int i = 0; i < 32; ++i) {
      int k = i * 8 + kb;
      float w0 = W[(size_t)k * 256 + nglob];
      float w1 = W[(size_t)(k + 1) * 256 + nglob];
      unsigned int pk = (unsigned int)f2bf(w0) | ((unsigned int)f2bf(w1) << 16);
      int ch = i ^ (n_ & 7);  // k>>3 == i
      *reinterpret_cast<unsigned int*>(&wt_lds[n_ * 512 + ch * 16 + (k & 7) * 2]) = pk;
    }
  }

  // ---- A-frags: 16 rows of X, fp32 -> bf16 in-reg (overlaps staging).
  bf16x8 a[8];
#pragma unroll
  for (int kk = 0; kk < 8; ++kk) {
    const f32x4* px =
        reinterpret_cast<const f32x4*>(X + (size_t)(rbase + c) * DD + kk * 32 + g * 8);
    f32x4 x0 = px[0], x1 = px[1];
    u16x8 v;
#pragma unroll
    for (int j = 0; j < 4; ++j) { v[j] = f2bf(x0[j]); v[4 + j] = f2bf(x1[j]); }
    a[kk] = __builtin_bit_cast(bf16x8, v);
  }
  __syncthreads();

#pragma unroll
  for (int ct0 = 0; ct0 < 4; ++ct0) {
    const int jrl = ct0 * 16 + c;  // local W^T row; jrl&7 == c&7
    f32x4 acc = {0.f, 0.f, 0.f, 0.f};
#pragma unroll
    for (int kk = 0; kk < 8; ++kk) {
      int ch = (kk * 4 + g) ^ (c & 7);
      bf16x8 b = *reinterpret_cast<const bf16x8*>(&wt_lds[jrl * 512 + ch * 16]);
      acc = __builtin_amdgcn_mfma_f32_16x16x32_bf16(a[kk], b, acc, 0, 0, 0);
    }
    int ct = ctbase + ct0;
#pragma unroll
    for (int r = 0; r < 4; ++r)
      OUT[(size_t)(rbase + g * 4 + r) * DD + ct * 16 + c] = f2bf(acc[r] * scale);
  }
}

// ---------------------------------------------------------------------------
// Kernel 2: flash-style scores + online base-2 logsumexp partials.
// R13-proven structure (44.0 us, absmax 0): grid (NQ/128, NSPLIT), 4 waves x
// 32 Q-rows, K tile [64x256] bf16 double-buffered, global_load_lds(16) with
// XOR chunk-swizzle on the GLOBAL source, counted vmcnt(8), raw barriers
// (no drain), two-accumulator fold overlap.  R14's pair-phase variant RACED
// (STAGE overwrote a buffer still being read) -> reverted.
// ---------------------------------------------------------------------------
__global__ __launch_bounds__(256, 2) void scores_lse_kernel(
    const ushort_t* __restrict__ Qb, const ushort_t* __restrict__ Kb,
    float* __restrict__ pm, float* __restrict__ ps) {
  __shared__ __align__(128) char smem[2][KBLK * 512];  // 64 KB
  const int tid = threadIdx.x;
  const int w = tid >> 6, lane = tid & 63;
  const int g = lane >> 4, c = lane & 15;
  const int qw = blockIdx.x * 128 + w * 32;
  const int j0 = blockIdx.y * SEG;

  // A-frags: 2 row-tiles x 8 k-steps (64 VGPRs, resident whole kernel).
  bf16x8 a[2][8];
#pragma unroll
  for (int rt = 0; rt < 2; ++rt)
#pragma unroll
    for (int kk = 0; kk < 8; ++kk) {
      u32x4 v = *reinterpret_cast<const u32x4*>(
          Qb + (size_t)(qw + rt * 16 + c) * DD + kk * 32 + g * 8);
      a[rt][kk] = __builtin_bit_cast(bf16x8, v);
    }
  asm volatile("s_waitcnt vmcnt(0)" ::: "memory");

  // hoisted per-lane ds_read bases (even/odd kk parity; R7 derivation)
  const int c2 = (c >> 2) & 1;
  const int lbase = c * 512 + ((g ^ (c & 3)) << 4);
  const int base_e = lbase + c2 * 64;
  const int base_o = lbase - c2 * 64;

  float m[2][4], s[2][4];
#pragma unroll
  for (int rt = 0; rt < 2; ++rt)
#pragma unroll
    for (int r = 0; r < 4; ++r) { m[rt][r] = -3.4e38f; s[rt][r] = 0.f; }

  f32x4 accA[2][4], accB[2][4];

  // stage tile t (64 rows, 32 KB): 4 waves x 8 gload_lds(16B) each.
  // LDS[row][ch] = K[row][ch^(row&7)] via swizzled GLOBAL source.
#define STAGE(buf, t)                                                          \
  do {                                                                         \
    const char* kbase_ = (const char*)(Kb + (size_t)(j0 + (t) * KBLK) * DD);   \
    _Pragma("unroll") for (int i_ = 0; i_ < 8; ++i_) {                         \
      int L_ = (w * 8 + i_) * 64 + lane;                                       \
      int row_ = L_ >> 5, ch_ = L_ & 31;                                       \
      const char* src_ = kbase_ + row_ * 512 + ((ch_ ^ (row_ & 7)) * 16);      \
      char* dst_ = &smem[buf][L_ * 16];                                        \
      __builtin_amdgcn_global_load_lds((gptr_t)src_, (lptr_t)dst_, 16, 0, 0);  \
    }                                                                          \
  } while (0)

  // reads+MFMA of one tile into acc set C (zero-init inside)
#define MFMA_TILE(buf, C)                                                      \
  do {                                                                         \
    const char* se_ = &smem[buf][0] + base_e;                                  \
    const char* so_ = &smem[buf][0] + base_o;                                  \
    _Pragma("unroll") for (int rt_ = 0; rt_ < 2; ++rt_)                        \
    _Pragma("unroll") for (int jt_ = 0; jt_ < 4; ++jt_)                        \
        C[rt_][jt_] = (f32x4){0.f, 0.f, 0.f, 0.f};                             \
    _Pragma("unroll") for (int kk_ = 0; kk_ < 8; kk_ += 2) {                   \
      _Pragma("unroll") for (int jt_ = 0; jt_ < 4; ++jt_) {                    \
        bf16x8 be_ = *reinterpret_cast<const bf16x8*>(se_ + jt_ * 8192 + kk_ * 64); \
        bf16x8 bo_ = *reinterpret_cast<const bf16x8*>(so_ + jt_ * 8192 + (kk_ + 1) * 64); \
        C[0][jt_] = __builtin_amdgcn_mfma_f32_16x16x32_bf16(a[0][kk_], be_, C[0][jt_], 0, 0, 0); \
        C[1][jt_] = __builtin_amdgcn_mfma_f32_16x16x32_bf16(a[1][kk_], be_, C[1][jt_], 0, 0, 0); \
        C[0][jt_] = __builtin_amdgcn_mfma_f32_16x16x32_bf16(a[0][kk_ + 1], bo_, C[0][jt_], 0, 0, 0); \
        C[1][jt_] = __builtin_amdgcn_mfma_f32_16x16x32_bf16(a[1][kk_ + 1], bo_, C[1][jt_], 0, 0, 0); \
      }                                                                        \
    }                                                                          \
  } while (0)

  // branchless grouped online-lse fold of acc set F (one basic block)
#define FOLD(F)                                                                \
  do {                                                                         \
    _Pragma("unroll") for (int rt_ = 0; rt_ < 2; ++rt_)                        \
    _Pragma("unroll") for (int r_ = 0; r_ < 4; ++r_) {                         \
      float v0_ = F[rt_][0][r_], v1_ = F[rt_][1][r_];                          \
      float v2_ = F[rt_][2][r_], v3_ = F[rt_][3][r_];                          \
      float tm_ = fmaxf(fmaxf(v0_, v1_), fmaxf(v2_, v3_));                     \
      float mo_ = m[rt_][r_];                                                  \
      float mn_ = fmaxf(mo_, tm_);                                             \
      float sc_ = fexp2(mo_ - mn_);                                            \
      s[rt_][r_] = s[rt_][r_] * sc_ +                                          \
                   (fexp2(v0_ - mn_) + fexp2(v1_ - mn_) +                      \
                    fexp2(v2_ - mn_) + fexp2(v3_ - mn_));                      \
      m[rt_][r_] = mn_;                                                        \
    }                                                                          \
  } while (0)

  // ---- prologue: tile 0 -> accA (no fold yet)
  STAGE(0, 0);
  STAGE(1, 1);
  asm volatile("s_waitcnt vmcnt(8)" ::: "memory");
  __builtin_amdgcn_s_barrier();
  MFMA_TILE(0, accA);
  asm volatile("s_waitcnt lgkmcnt(0)" ::: "memory");
  __builtin_amdgcn_s_barrier();

  // ---- main loop: tiles 1..NT-2 in pairs (NT=16: tt = 1,3,...,13)
#pragma unroll 1
  for (int tt = 1; tt + 1 < NT; tt += 2) {
    // tile tt (buf1) -> accB; fold accA (tile tt-1) overlaps the vmcnt wait
    STAGE(0, tt + 1);
    FOLD(accA);
    asm volatile("s_waitcnt vmcnt(8)" ::: "memory");
    __builtin_amdgcn_s_barrier();
    MFMA_TILE(1, accB);
    asm volatile("s_waitcnt lgkmcnt(0)" ::: "memory");
    __builtin_amdgcn_s_barrier();

    // tile tt+1 (buf0) -> accA; fold accB (tile tt)
    STAGE(1, tt + 2);
    FOLD(accB);
    asm volatile("s_waitcnt vmcnt(8)" ::: "memory");
    __builtin_amdgcn_s_barrier();
    MFMA_TILE(0, accA);
    asm volatile("s_waitcnt lgkmcnt(0)" ::: "memory");
    __builtin_amdgcn_s_barrier();
  }

  // ---- epilogue: tile NT-1 (buf1) -> accB; folds of last two acc sets
  FOLD(accA);
  asm volatile("s_waitcnt vmcnt(0)" ::: "memory");
  __builtin_amdgcn_s_barrier();
  MFMA_TILE(1, accB);
  FOLD(accB);
#undef STAGE
#undef MFMA_TILE
#undef FOLD

  // merge the 16 lanes of each group (each held a 4-col-stride slice)
#pragma unroll
  for (int rt = 0; rt < 2; ++rt)
#pragma unroll
    for (int r = 0; r < 4; ++r) {
      float M = m[rt][r], S = s[rt][r];
#pragma unroll
      for (int off = 1; off < 16; off <<= 1) {
        float Mo = __shfl_xor(M, off);
        float So = __shfl_xor(S, off);
        float Mn = fmaxf(M, Mo);
        S = S * fexp2(M - Mn) + So * fexp2(Mo - Mn);
        M = Mn;
      }
      if (c == 0) {
        int row = qw + rt * 16 + g * 4 + r;
        pm[blockIdx.y * NQ + row] = M;
        ps[blockIdx.y * NQ + row] = S;
      }
    }
}

// ---------------------------------------------------------------------------
// Kernel 3: per-row lse (base-2 partials -> natural), block-sum -> part[64]
// ---------------------------------------------------------------------------
__global__ __launch_bounds__(128) void finalize1_kernel(
    const float* __restrict__ pm, const float* __restrict__ ps,
    float* __restrict__ part) {
  const int tid = threadIdx.x;
  const int row = blockIdx.x * 128 + tid;
  float M = -3.4e38f;
#pragma unroll
  for (int k = 0; k < NSPLIT; ++k) M = fmaxf(M, pm[k * NQ + row]);
  float S = 0.f;
#pragma unroll
  for (int k = 0; k < NSPLIT; ++k) S += ps[k * NQ + row] * fexp2(pm[k * NQ + row] - M);
  float v = LN2 * (M + flog2(S));

  __shared__ float red[128];
  red[tid] = v;
  __syncthreads();
#pragma unroll
  for (int st = 64; st > 0; st >>= 1) {
    if (tid < st) red[tid] += red[tid + st];
    __syncthreads();
  }
  if (tid == 0) part[blockIdx.x] = red[0];
}

// ---------------------------------------------------------------------------
// Kernel 4: sum 64 partials, negate.
// ---------------------------------------------------------------------------
__global__ __launch_bounds__(64) void finalize2_kernel(
    const float* __restrict__ part, float* __restrict__ out) {
  const int lane = threadIdx.x;
  float v = part[lane];
#pragma unroll
  for (int off = 1; off < 64; off <<= 1) v += __shfl_xor(v, off);
  if (lane == 0) out[0] = -v;
}

// ---------------------------------------------------------------------------
extern "C" void kernel_launch(void* const* d_in, const int* in_sizes, int n_in,
                              void* d_out, int out_size, void* d_ws, size_t ws_size,
                              hipStream_t stream) {
  const float* xq = (const float*)d_in[0];
  const float* xk = (const float*)d_in[1];
  const float* Wq = (const float*)d_in[2];
  const float* Wk = (const float*)d_in[3];

  char* ws = (char*)d_ws;
  // ws: Qb 4MB | Kb 4MB | pm 256KB | ps 256KB | part 256B
  ushort_t* Qb = (ushort_t*)(ws);
  ushort_t* Kb = (ushort_t*)(ws + (size_t)NQ * DD * 2);
  float* pm = (float*)(ws + (size_t)(NQ + NK) * DD * 2);
  float* ps = pm + (size_t)NSPLIT * NQ;
  float* part = ps + (size_t)NSPLIT * NQ;

  hipLaunchKernelGGL(proj_kernel, dim3(128, 2, 4), dim3(256), 0, stream,
                     xq, xk, Wq, Wk, Qb, Kb);
  hipLaunchKernelGGL(scores_lse_kernel, dim3(NQ / 128, NSPLIT), dim3(256), 0, stream,
                     Qb, Kb, pm, ps);
  hipLaunchKernelGGL(finalize1_kernel, dim3(64), dim3(128), 0, stream, pm, ps, part);
  hipLaunchKernelGGL(finalize2_kernel, dim3(1), dim3(64), 0, stream, part, (float*)d_out);
}